// Round 6
// baseline (631.689 us; speedup 1.0000x reference)
//
#include <hip/hip_runtime.h>
#include <hip/hip_fp16.h>
#include <math.h>

#define ITERS 12

typedef __attribute__((ext_vector_type(8))) short short8;
typedef __attribute__((ext_vector_type(4))) float float4v;

// AGPR park/unpark (gfx950 unified file: MFMA kernels split the per-wave
// budget ~half arch / half accum; scores live in the accum half so the arch
// half never spills).  volatile: stops loop-invariant AREADs being hoisted
// (which would re-materialize the whole array in arch VGPRs).
#define AWRITE(dst, src) \
    asm volatile("v_accvgpr_write_b32 %0, %1" : "=a"(dst) : "v"(src))
#define AREAD(dst, src) \
    asm volatile("v_accvgpr_read_b32 %0, %1" : "=v"(dst) : "a"(src))

static __device__ inline unsigned short f2bf(float f) {
    union { float f; unsigned int u; } c; c.f = f;
    unsigned int u = c.u;
    u += 0x7fffu + ((u >> 16) & 1u);          // round-to-nearest-even
    return (unsigned short)(u >> 16);
}
static __device__ inline float bf2f(unsigned short h) {
    union { float f; unsigned int u; } c; c.u = ((unsigned int)h) << 16;
    return c.f;
}

// ---------------------------------------------------------------------------
// Kernel A (unchanged): P = l2_normalize(X @ W^T + b), emitted as split-bf16
// rows of 192:
//   sub:  [hi(64) | lo(64) | hi(64)]
//   edge: [hi(64) | hi(64) | lo(64)]
// so that subE @ edgeE^T over K=192 = Ah*Bh + Al*Bh + Ah*Bl (lo*lo dropped).
// ---------------------------------------------------------------------------
__global__ __launch_bounds__(256) void proj_norm_kernel(
    const float* __restrict__ Xsub, const float* __restrict__ Xedge,
    const float* __restrict__ Wsub, const float* __restrict__ bsub,
    const float* __restrict__ Wedge, const float* __restrict__ bedge,
    unsigned short* __restrict__ subE, unsigned short* __restrict__ edgeE)
{
    const int mat = blockIdx.y;
    const float* X  = mat ? Xedge : Xsub;
    const float* W  = mat ? Wedge : Wsub;
    const float* Bv = mat ? bedge : bsub;
    unsigned short* OUT = mat ? edgeE : subE;

    const int r0 = blockIdx.x * 32;
    const int t  = threadIdx.x;
    const int tx = t & 15, ty = t >> 4;

    __shared__ float xs[64 * 34];   // [k][row(32)+pad]
    __shared__ float ws[64 * 68];   // [k][col(64)+pad]

    float acc[2][4] = {};

    for (int ch = 0; ch < 8; ++ch) {
        const int kb = ch * 64;
#pragma unroll
        for (int i = 0; i < 2; ++i) {
            int e = t + 256 * i;            // 512 float4 (32 rows x 16 kq)
            int row = e & 31, kq = e >> 5;
            float4 xv = *(const float4*)(X + (size_t)(r0 + row) * 512 + kb + kq * 4);
            xs[(kq * 4 + 0) * 34 + row] = xv.x;
            xs[(kq * 4 + 1) * 34 + row] = xv.y;
            xs[(kq * 4 + 2) * 34 + row] = xv.z;
            xs[(kq * 4 + 3) * 34 + row] = xv.w;
        }
#pragma unroll
        for (int i = 0; i < 4; ++i) {
            int e = t + 256 * i;            // 1024 float4 (64 cols x 16 kq)
            int col = e & 63, kq = e >> 6;
            float4 wv = *(const float4*)(W + (size_t)col * 512 + kb + kq * 4);
            ws[(kq * 4 + 0) * 68 + col] = wv.x;
            ws[(kq * 4 + 1) * 68 + col] = wv.y;
            ws[(kq * 4 + 2) * 68 + col] = wv.z;
            ws[(kq * 4 + 3) * 68 + col] = wv.w;
        }
        __syncthreads();
#pragma unroll 8
        for (int k = 0; k < 64; ++k) {
            const float2 a2 = *(const float2*)&xs[k * 34 + ty * 2];
            const float4 b4 = *(const float4*)&ws[k * 68 + tx * 4];
            acc[0][0] = fmaf(a2.x, b4.x, acc[0][0]);
            acc[0][1] = fmaf(a2.x, b4.y, acc[0][1]);
            acc[0][2] = fmaf(a2.x, b4.z, acc[0][2]);
            acc[0][3] = fmaf(a2.x, b4.w, acc[0][3]);
            acc[1][0] = fmaf(a2.y, b4.x, acc[1][0]);
            acc[1][1] = fmaf(a2.y, b4.y, acc[1][1]);
            acc[1][2] = fmaf(a2.y, b4.z, acc[1][2]);
            acc[1][3] = fmaf(a2.y, b4.w, acc[1][3]);
        }
        __syncthreads();
    }

    const float4 bb = *(const float4*)(Bv + tx * 4);
#pragma unroll
    for (int i = 0; i < 2; ++i) {
        acc[i][0] += bb.x; acc[i][1] += bb.y; acc[i][2] += bb.z; acc[i][3] += bb.w;
        float s = acc[i][0]*acc[i][0] + acc[i][1]*acc[i][1]
                + acc[i][2]*acc[i][2] + acc[i][3]*acc[i][3];
#pragma unroll
        for (int off = 1; off <= 8; off <<= 1)
            s += __shfl_xor(s, off, 64);
        const float inv = 1.0f / fmaxf(sqrtf(s), 1e-12f);

        unsigned short h[4], l[4];
#pragma unroll
        for (int j = 0; j < 4; ++j) {
            const float v = acc[i][j] * inv;
            h[j] = f2bf(v);
            l[j] = f2bf(v - bf2f(h[j]));
        }
        uint2 hp, lp;
        hp.x = (unsigned)h[0] | ((unsigned)h[1] << 16);
        hp.y = (unsigned)h[2] | ((unsigned)h[3] << 16);
        lp.x = (unsigned)l[0] | ((unsigned)l[1] << 16);
        lp.y = (unsigned)l[2] | ((unsigned)l[3] << 16);

        unsigned short* base = OUT + (size_t)(r0 + ty * 2 + i) * 192 + tx * 4;
        *(uint2*)(base)       = hp;
        *(uint2*)(base + 64)  = mat ? hp : lp;   // edge: hi ; sub: lo
        *(uint2*)(base + 128) = mat ? lp : hp;   // edge: lo ; sub: hi
    }
}

// ---------------------------------------------------------------------------
// Kernel F (v5): FUSED scores + entmax, occupancy-doubled.
//   r5 evidence: 512-thr/8-wave blocks at 256 regs/wave -> 2 waves/SIMD
//   (Occupancy 22%), latency-bound (VALU 37%, stalls 63%).  v5 uses
//   1024-thr/16-wave blocks: budget 128/wave splits 64 arch + 64 accum;
//   wave owns 512 edge cols = 32 tiles -> zh[64] packed fp16 = exactly the
//   64 AGPRs (parked via v_accvgpr asm, proven in r5); arch side holds only
//   bf[6] (24) + GEMM temps.  -> 4 waves/SIMD, 2x latency hiding.
//   Row-max is folded into the GEMM phase (f32 max in the MFMA shadow; the
//   <=5e-4 f32-vs-fp16 gap self-corrects in one support iteration since
//   tau0=m-1 only needs to be a sane starting point).
//   SWAPPED MFMA (D col = sub row): each lane owns ONE row; tau/n/s1/s2
//   scalars; reduce = shfl_xor(16,32) + redS[2][16][16] table, 1 barrier/it.
//   Numerics: __float2half_rn quantization + exact quadratic solve (r3/r5).
// ---------------------------------------------------------------------------
__global__ __launch_bounds__(1024) void fused_score_entmax_kernel(
    const unsigned short* __restrict__ subE,
    const unsigned short* __restrict__ edgeE,
    const float* __restrict__ log_scale,
    float* __restrict__ out)
{
    const int t    = threadIdx.x;
    const int lane = t & 63;
    const int wid  = t >> 6;        // 0..15
    const int li   = lane & 15;     // sub-row owned by this lane
    const int quad = lane >> 4;     // 0..3
    const int r0   = blockIdx.x * 16;
    const int c0   = wid * 512;     // edge-col base of this wave

    __shared__ float4 redS[2][16][16];   // [buf][wave][row] = {n,s1,s2,-}

    // ---- B fragments: subE rows r0..r0+15, K=192 (all waves same 6 KB) ----
    short8 bf[6];
#pragma unroll
    for (int kk = 0; kk < 6; ++kk)
        bf[kk] = *(const short8*)(subE + (size_t)(r0 + li) * 192 + kk * 32 + quad * 8);

    float sc = expf(log_scale[0]);
    sc = fminf(fmaxf(sc, 0.5f), 20.0f);
    const float zs = sc * 0.5f;          // z = scores/2

    // ---- GEMM: 32 tiles/wave; scores packed fp16 -> AGPRs zh[64];
    //      row-max tracked on f32 values in the MFMA shadow ----
    unsigned zh[64];                     // AGPR-resident (via AWRITE/AREAD)
    float m = -1e30f;

#pragma unroll
    for (int tp = 0; tp < 32; ++tp) {
        const unsigned short* ap = edgeE + (size_t)(c0 + tp * 16 + li) * 192 + quad * 8;
        float4v acc = (float4v){0.f, 0.f, 0.f, 0.f};
#pragma unroll
        for (int kk = 0; kk < 6; ++kk) {
            short8 af = *(const short8*)(ap + kk * 32);
            acc = __builtin_amdgcn_mfma_f32_16x16x32_bf16(af, bf[kk], acc, 0, 0, 0);
        }
        const float z0 = acc[0] * zs, z1 = acc[1] * zs;
        const float z2 = acc[2] * zs, z3 = acc[3] * zs;
        m = fmaxf(m, fmaxf(fmaxf(z0, z1), fmaxf(z2, z3)));
        union { unsigned u; __half2 h2; } c01, c23;
        c01.h2.x = __float2half_rn(z0);
        c01.h2.y = __float2half_rn(z1);
        c23.h2.x = __float2half_rn(z2);
        c23.h2.y = __float2half_rn(z3);
        AWRITE(zh[tp * 2 + 0], c01.u);
        AWRITE(zh[tp * 2 + 1], c23.u);
    }

    // ---- combine row max across the 4 quads + 16 waves -> tau0 = m - 1 ----
    m = fmaxf(m, __shfl_xor(m, 16, 64));
    m = fmaxf(m, __shfl_xor(m, 32, 64));
    if (quad == 0) redS[0][wid][li] = (float4){m, 0.f, 0.f, 0.f};
    __syncthreads();
    {
        float mw = redS[0][quad * 4 + 0][li].x;
        mw = fmaxf(mw, redS[0][quad * 4 + 1][li].x);
        mw = fmaxf(mw, redS[0][quad * 4 + 2][li].x);
        mw = fmaxf(mw, redS[0][quad * 4 + 3][li].x);
        mw = fmaxf(mw, __shfl_xor(mw, 16, 64));
        mw = fmaxf(mw, __shfl_xor(mw, 32, 64));
        m = mw;
    }
    float tau = m - 1.0f;

    // ---- support-set iteration, exact quadratic solve, 1 barrier/iter ----
    int buf = 1;                         // iter 0 writes redS[1] (max used [0])
    for (int it = 0; it < ITERS; ++it) {
        float n = 0.f, s1 = 0.f, s2 = 0.f;
#pragma unroll
        for (int j = 0; j < 64; ++j) {
            union { unsigned u; __half2 h2; } cv;
            AREAD(cv.u, zh[j]);
            float2 f = __half22float2(cv.h2);
            {
                const bool  p  = f.x > tau;
                const float zm = p ? f.x : 0.f;
                n  += p ? 1.f : 0.f;
                s1 += zm;
                s2  = fmaf(zm, f.x, s2);
            }
            {
                const bool  p  = f.y > tau;
                const float zm = p ? f.y : 0.f;
                n  += p ? 1.f : 0.f;
                s1 += zm;
                s2  = fmaf(zm, f.y, s2);
            }
        }
        // combine the 4 lanes owning row li within this wave
        n  += __shfl_xor(n, 16, 64);  n  += __shfl_xor(n, 32, 64);
        s1 += __shfl_xor(s1, 16, 64); s1 += __shfl_xor(s1, 32, 64);
        s2 += __shfl_xor(s2, 16, 64); s2 += __shfl_xor(s2, 32, 64);
        if (quad == 0) redS[buf][wid][li] = (float4){n, s1, s2, 0.f};
        __syncthreads();

        // every lane gathers 4 waves' partials, combines quads via shfl
        float4 p0 = redS[buf][quad * 4 + 0][li];
        float4 p1 = redS[buf][quad * 4 + 1][li];
        float4 p2 = redS[buf][quad * 4 + 2][li];
        float4 p3 = redS[buf][quad * 4 + 3][li];
        float N  = p0.x + p1.x + p2.x + p3.x;
        float S1 = p0.y + p1.y + p2.y + p3.y;
        float S2 = p0.z + p1.z + p2.z + p3.z;
        N  += __shfl_xor(N, 16, 64);  N  += __shfl_xor(N, 32, 64);
        S1 += __shfl_xor(S1, 16, 64); S1 += __shfl_xor(S1, 32, 64);
        S2 += __shfl_xor(S2, 16, 64); S2 += __shfl_xor(S2, 32, 64);

        const float disc = S1 * S1 - N * (S2 - 1.0f);
        float tn;
        if (disc >= 0.0f) {
            tn = (S1 - sqrtf(disc)) / N;
        } else {
            const float g = S1 - N * tau;
            const float f = S2 - tau * (2.0f * S1 - N * tau);
            tn = tau + (f - 1.0f) / (2.0f * g);
        }
        const bool cf = (tn == tau);
        tau = tn;
        buf ^= 1;
        if (__all(cf)) break;            // identical in every wave
    }

    // ---- emit p = clip(z - tau, 0)^2, float4v nontemporal stores ----
    float* orow = out + (size_t)(r0 + li) * 8192 + c0;
#pragma unroll
    for (int tp = 0; tp < 32; ++tp) {
        union { unsigned u; __half2 h2; } c01, c23;
        AREAD(c01.u, zh[tp * 2 + 0]);
        AREAD(c23.u, zh[tp * 2 + 1]);
        float2 f01 = __half22float2(c01.h2);
        float2 f23 = __half22float2(c23.h2);
        float4v pv;
        float d;
        d = fmaxf(f01.x - tau, 0.f); pv.x = d * d;
        d = fmaxf(f01.y - tau, 0.f); pv.y = d * d;
        d = fmaxf(f23.x - tau, 0.f); pv.z = d * d;
        d = fmaxf(f23.y - tau, 0.f); pv.w = d * d;
        __builtin_nontemporal_store(pv, (float4v*)(orow + tp * 16 + quad * 4));
    }
}

// ---------------------------------------------------------------------------
extern "C" void kernel_launch(void* const* d_in, const int* in_sizes, int n_in,
                              void* d_out, int out_size, void* d_ws, size_t ws_size,
                              hipStream_t stream)
{
    const float* edge_repr = (const float*)d_in[0];
    const float* sub_repr  = (const float*)d_in[1];
    const float* W_sub     = (const float*)d_in[2];
    const float* b_sub     = (const float*)d_in[3];
    const float* W_edge    = (const float*)d_in[4];
    const float* b_edge    = (const float*)d_in[5];
    const float* log_scale = (const float*)d_in[6];
    float* out = (float*)d_out;

    unsigned short* subE  = (unsigned short*)d_ws;                 // 3 MB
    unsigned short* edgeE = subE + (size_t)8192 * 192;             // 3 MB

    proj_norm_kernel<<<dim3(256, 2), 256, 0, stream>>>(
        sub_repr, edge_repr, W_sub, b_sub, W_edge, b_edge, subE, edgeE);

    fused_score_entmax_kernel<<<dim3(512), 1024, 0, stream>>>(
        subE, edgeE, log_scale, out);
}

// Round 7
// 617.739 us; speedup vs baseline: 1.0226x; 1.0226x over previous
//
#include <hip/hip_runtime.h>
#include <hip/hip_fp16.h>
#include <math.h>

#define ITERS 12

typedef __attribute__((ext_vector_type(8))) short short8;
typedef __attribute__((ext_vector_type(4))) float float4v;
typedef _Float16 __attribute__((ext_vector_type(2))) half2v;

// Batched AGPR park/unpark: 4 moves per asm volatile block -> 4x fewer
// scheduling barriers / hazard brackets than per-word asm (r6 evidence:
// wall invariant to occupancy => per-wave issue bound; accvgpr asm overhead
// scales with total work exactly like the observed invariance).
#define AWRITE4(d0, d1, d2, d3, s0, s1, s2, s3)            \
    asm volatile("v_accvgpr_write_b32 %0, %4\n\t"          \
                 "v_accvgpr_write_b32 %1, %5\n\t"          \
                 "v_accvgpr_write_b32 %2, %6\n\t"          \
                 "v_accvgpr_write_b32 %3, %7"              \
                 : "=a"(d0), "=a"(d1), "=a"(d2), "=a"(d3)  \
                 : "v"(s0), "v"(s1), "v"(s2), "v"(s3))
#define AREAD4(d0, d1, d2, d3, s0, s1, s2, s3)             \
    asm volatile("v_accvgpr_read_b32 %0, %4\n\t"           \
                 "v_accvgpr_read_b32 %1, %5\n\t"           \
                 "v_accvgpr_read_b32 %2, %6\n\t"           \
                 "v_accvgpr_read_b32 %3, %7"               \
                 : "=v"(d0), "=v"(d1), "=v"(d2), "=v"(d3)  \
                 : "a"(s0), "a"(s1), "a"(s2), "a"(s3))

static __device__ inline unsigned short f2bf(float f) {
    union { float f; unsigned int u; } c; c.f = f;
    unsigned int u = c.u;
    u += 0x7fffu + ((u >> 16) & 1u);          // round-to-nearest-even
    return (unsigned short)(u >> 16);
}
static __device__ inline float bf2f(unsigned short h) {
    union { float f; unsigned int u; } c; c.u = ((unsigned int)h) << 16;
    return c.f;
}

// ---------------------------------------------------------------------------
// Kernel A (unchanged): P = l2_normalize(X @ W^T + b), emitted as split-bf16
// rows of 192:
//   sub:  [hi(64) | lo(64) | hi(64)]
//   edge: [hi(64) | hi(64) | lo(64)]
// so that subE @ edgeE^T over K=192 = Ah*Bh + Al*Bh + Ah*Bl (lo*lo dropped).
// ---------------------------------------------------------------------------
__global__ __launch_bounds__(256) void proj_norm_kernel(
    const float* __restrict__ Xsub, const float* __restrict__ Xedge,
    const float* __restrict__ Wsub, const float* __restrict__ bsub,
    const float* __restrict__ Wedge, const float* __restrict__ bedge,
    unsigned short* __restrict__ subE, unsigned short* __restrict__ edgeE)
{
    const int mat = blockIdx.y;
    const float* X  = mat ? Xedge : Xsub;
    const float* W  = mat ? Wedge : Wsub;
    const float* Bv = mat ? bedge : bsub;
    unsigned short* OUT = mat ? edgeE : subE;

    const int r0 = blockIdx.x * 32;
    const int t  = threadIdx.x;
    const int tx = t & 15, ty = t >> 4;

    __shared__ float xs[64 * 34];   // [k][row(32)+pad]
    __shared__ float ws[64 * 68];   // [k][col(64)+pad]

    float acc[2][4] = {};

    for (int ch = 0; ch < 8; ++ch) {
        const int kb = ch * 64;
#pragma unroll
        for (int i = 0; i < 2; ++i) {
            int e = t + 256 * i;            // 512 float4 (32 rows x 16 kq)
            int row = e & 31, kq = e >> 5;
            float4 xv = *(const float4*)(X + (size_t)(r0 + row) * 512 + kb + kq * 4);
            xs[(kq * 4 + 0) * 34 + row] = xv.x;
            xs[(kq * 4 + 1) * 34 + row] = xv.y;
            xs[(kq * 4 + 2) * 34 + row] = xv.z;
            xs[(kq * 4 + 3) * 34 + row] = xv.w;
        }
#pragma unroll
        for (int i = 0; i < 4; ++i) {
            int e = t + 256 * i;            // 1024 float4 (64 cols x 16 kq)
            int col = e & 63, kq = e >> 6;
            float4 wv = *(const float4*)(W + (size_t)col * 512 + kb + kq * 4);
            ws[(kq * 4 + 0) * 68 + col] = wv.x;
            ws[(kq * 4 + 1) * 68 + col] = wv.y;
            ws[(kq * 4 + 2) * 68 + col] = wv.z;
            ws[(kq * 4 + 3) * 68 + col] = wv.w;
        }
        __syncthreads();
#pragma unroll 8
        for (int k = 0; k < 64; ++k) {
            const float2 a2 = *(const float2*)&xs[k * 34 + ty * 2];
            const float4 b4 = *(const float4*)&ws[k * 68 + tx * 4];
            acc[0][0] = fmaf(a2.x, b4.x, acc[0][0]);
            acc[0][1] = fmaf(a2.x, b4.y, acc[0][1]);
            acc[0][2] = fmaf(a2.x, b4.z, acc[0][2]);
            acc[0][3] = fmaf(a2.x, b4.w, acc[0][3]);
            acc[1][0] = fmaf(a2.y, b4.x, acc[1][0]);
            acc[1][1] = fmaf(a2.y, b4.y, acc[1][1]);
            acc[1][2] = fmaf(a2.y, b4.z, acc[1][2]);
            acc[1][3] = fmaf(a2.y, b4.w, acc[1][3]);
        }
        __syncthreads();
    }

    const float4 bb = *(const float4*)(Bv + tx * 4);
#pragma unroll
    for (int i = 0; i < 2; ++i) {
        acc[i][0] += bb.x; acc[i][1] += bb.y; acc[i][2] += bb.z; acc[i][3] += bb.w;
        float s = acc[i][0]*acc[i][0] + acc[i][1]*acc[i][1]
                + acc[i][2]*acc[i][2] + acc[i][3]*acc[i][3];
#pragma unroll
        for (int off = 1; off <= 8; off <<= 1)
            s += __shfl_xor(s, off, 64);
        const float inv = 1.0f / fmaxf(sqrtf(s), 1e-12f);

        unsigned short h[4], l[4];
#pragma unroll
        for (int j = 0; j < 4; ++j) {
            const float v = acc[i][j] * inv;
            h[j] = f2bf(v);
            l[j] = f2bf(v - bf2f(h[j]));
        }
        uint2 hp, lp;
        hp.x = (unsigned)h[0] | ((unsigned)h[1] << 16);
        hp.y = (unsigned)h[2] | ((unsigned)h[3] << 16);
        lp.x = (unsigned)l[0] | ((unsigned)l[1] << 16);
        lp.y = (unsigned)l[2] | ((unsigned)l[3] << 16);

        unsigned short* base = OUT + (size_t)(r0 + ty * 2 + i) * 192 + tx * 4;
        *(uint2*)(base)       = hp;
        *(uint2*)(base + 64)  = mat ? hp : lp;   // edge: hi ; sub: lo
        *(uint2*)(base + 128) = mat ? lp : hp;   // edge: lo ; sub: hi
    }
}

// ---------------------------------------------------------------------------
// Kernel F (v6): FUSED scores + entmax, issue-count-reduced.
//   r6 evidence: wall (388 us) invariant to 2x occupancy change at equal
//   total work -> per-wave ISSUE bound, with VALUBusy only 38% -> dead issue
//   slots (s_nop hazard brackets + sched barriers around per-word
//   asm-volatile accvgpr moves) + fat f32 scan loop.  v6 attacks both:
//   (1) AGPR moves batched 4/asm block (AREAD4/AWRITE4);
//   (2) support scan in packed fp16: hgt2 mask, hmul2 masked-z, hadd2
//       packed count (exact: <=64 per slot), v_dot2_f32_f16 for s1/s2
//       (f32 accumulate; fp16*fp16 exact in f32)  ~13 -> ~5.5 ops/word.
//       Membership compare moves f32->fp16; borderline flips shift tau by
//       O(ulp/N) -> out delta << 1e-4.
//   (3) GEMM 2-tile unroll (MFMA ILP + load pipelining, feeds AWRITE4).
//   Geometry/numerics otherwise = r6 (passed): 1024 thr / 16 waves /
//   16 rows / 512 cols per wave; zh[64] packed fp16 in AGPRs; swapped MFMA
//   (lane owns ONE row); exact quadratic tau solve; ITERS=12 + early break.
// ---------------------------------------------------------------------------
__global__ __launch_bounds__(1024) void fused_score_entmax_kernel(
    const unsigned short* __restrict__ subE,
    const unsigned short* __restrict__ edgeE,
    const float* __restrict__ log_scale,
    float* __restrict__ out)
{
    const int t    = threadIdx.x;
    const int lane = t & 63;
    const int wid  = t >> 6;        // 0..15
    const int li   = lane & 15;     // sub-row owned by this lane
    const int quad = lane >> 4;     // 0..3
    const int r0   = blockIdx.x * 16;
    const int c0   = wid * 512;     // edge-col base of this wave

    __shared__ float4 redS[2][16][16];   // [buf][wave][row] = {n,s1,s2,-}

    // ---- B fragments: subE rows r0..r0+15, K=192 (all waves same 6 KB) ----
    short8 bf[6];
#pragma unroll
    for (int kk = 0; kk < 6; ++kk)
        bf[kk] = *(const short8*)(subE + (size_t)(r0 + li) * 192 + kk * 32 + quad * 8);

    float sc = expf(log_scale[0]);
    sc = fminf(fmaxf(sc, 0.5f), 20.0f);
    const float zs = sc * 0.5f;          // z = scores/2

    // ---- GEMM: 32 tiles/wave, 2-tile unrolled; scores fp16 -> AGPR zh[64];
    //      row-max tracked on f32 values in the MFMA shadow ----
    unsigned zh[64];                     // AGPR-resident
    float m = -1e30f;

#pragma unroll
    for (int tp = 0; tp < 32; tp += 2) {
        const unsigned short* apA = edgeE + (size_t)(c0 + tp * 16 + li) * 192 + quad * 8;
        const unsigned short* apB = apA + 16 * 192;
        float4v accA = (float4v){0.f, 0.f, 0.f, 0.f};
        float4v accB = (float4v){0.f, 0.f, 0.f, 0.f};
#pragma unroll
        for (int kk = 0; kk < 6; ++kk) {
            short8 afA = *(const short8*)(apA + kk * 32);
            accA = __builtin_amdgcn_mfma_f32_16x16x32_bf16(afA, bf[kk], accA, 0, 0, 0);
        }
#pragma unroll
        for (int kk = 0; kk < 6; ++kk) {
            short8 afB = *(const short8*)(apB + kk * 32);
            accB = __builtin_amdgcn_mfma_f32_16x16x32_bf16(afB, bf[kk], accB, 0, 0, 0);
        }
        const float a0 = accA[0] * zs, a1 = accA[1] * zs;
        const float a2 = accA[2] * zs, a3 = accA[3] * zs;
        const float b0 = accB[0] * zs, b1 = accB[1] * zs;
        const float b2 = accB[2] * zs, b3 = accB[3] * zs;
        m = fmaxf(m, fmaxf(fmaxf(a0, a1), fmaxf(a2, a3)));
        m = fmaxf(m, fmaxf(fmaxf(b0, b1), fmaxf(b2, b3)));
        union { unsigned u; __half2 h2; } cA01, cA23, cB01, cB23;
        cA01.h2.x = __float2half_rn(a0); cA01.h2.y = __float2half_rn(a1);
        cA23.h2.x = __float2half_rn(a2); cA23.h2.y = __float2half_rn(a3);
        cB01.h2.x = __float2half_rn(b0); cB01.h2.y = __float2half_rn(b1);
        cB23.h2.x = __float2half_rn(b2); cB23.h2.y = __float2half_rn(b3);
        AWRITE4(zh[tp * 2 + 0], zh[tp * 2 + 1], zh[tp * 2 + 2], zh[tp * 2 + 3],
                cA01.u, cA23.u, cB01.u, cB23.u);
    }

    // ---- combine row max across the 4 quads + 16 waves -> tau0 = m - 1 ----
    m = fmaxf(m, __shfl_xor(m, 16, 64));
    m = fmaxf(m, __shfl_xor(m, 32, 64));
    if (quad == 0) redS[0][wid][li] = (float4){m, 0.f, 0.f, 0.f};
    __syncthreads();
    {
        float mw = redS[0][quad * 4 + 0][li].x;
        mw = fmaxf(mw, redS[0][quad * 4 + 1][li].x);
        mw = fmaxf(mw, redS[0][quad * 4 + 2][li].x);
        mw = fmaxf(mw, redS[0][quad * 4 + 3][li].x);
        mw = fmaxf(mw, __shfl_xor(mw, 16, 64));
        mw = fmaxf(mw, __shfl_xor(mw, 32, 64));
        m = mw;
    }
    float tau = m - 1.0f;

    const half2v one2v = {(_Float16)1.0f, (_Float16)1.0f};

    // ---- support-set iteration, packed-fp16 scan, 1 barrier/iter ----
    int buf = 1;                         // iter 0 writes redS[1] (max used [0])
    for (int it = 0; it < ITERS; ++it) {
        float s1 = 0.f, s2 = 0.f;
        __half2 nh2 = __float2half2_rn(0.f);
        const __half2 tau2 = __float2half2_rn(tau);
#pragma unroll
        for (int jb = 0; jb < 16; ++jb) {
            union U { unsigned u; __half2 h2; half2v v; };
            U a0, a1, a2, a3, m0, m1, m2_, m3, z0, z1, z2_, z3;
            AREAD4(a0.u, a1.u, a2.u, a3.u,
                   zh[jb * 4 + 0], zh[jb * 4 + 1], zh[jb * 4 + 2], zh[jb * 4 + 3]);
            m0.h2  = __hgt2(a0.h2, tau2);  z0.h2  = __hmul2(m0.h2,  a0.h2);
            m1.h2  = __hgt2(a1.h2, tau2);  z1.h2  = __hmul2(m1.h2,  a1.h2);
            m2_.h2 = __hgt2(a2.h2, tau2);  z2_.h2 = __hmul2(m2_.h2, a2.h2);
            m3.h2  = __hgt2(a3.h2, tau2);  z3.h2  = __hmul2(m3.h2,  a3.h2);
            nh2 = __hadd2(nh2, m0.h2);  nh2 = __hadd2(nh2, m1.h2);
            nh2 = __hadd2(nh2, m2_.h2); nh2 = __hadd2(nh2, m3.h2);
            s1 = __builtin_amdgcn_fdot2(z0.v,  one2v, s1, false);
            s2 = __builtin_amdgcn_fdot2(z0.v,  z0.v,  s2, false);
            s1 = __builtin_amdgcn_fdot2(z1.v,  one2v, s1, false);
            s2 = __builtin_amdgcn_fdot2(z1.v,  z1.v,  s2, false);
            s1 = __builtin_amdgcn_fdot2(z2_.v, one2v, s1, false);
            s2 = __builtin_amdgcn_fdot2(z2_.v, z2_.v, s2, false);
            s1 = __builtin_amdgcn_fdot2(z3.v,  one2v, s1, false);
            s2 = __builtin_amdgcn_fdot2(z3.v,  z3.v,  s2, false);
        }
        float2 nf = __half22float2(nh2);
        float n = nf.x + nf.y;

        // combine the 4 lanes owning row li within this wave
        n  += __shfl_xor(n, 16, 64);  n  += __shfl_xor(n, 32, 64);
        s1 += __shfl_xor(s1, 16, 64); s1 += __shfl_xor(s1, 32, 64);
        s2 += __shfl_xor(s2, 16, 64); s2 += __shfl_xor(s2, 32, 64);
        if (quad == 0) redS[buf][wid][li] = (float4){n, s1, s2, 0.f};
        __syncthreads();

        // every lane gathers 4 waves' partials, combines quads via shfl
        float4 p0 = redS[buf][quad * 4 + 0][li];
        float4 p1 = redS[buf][quad * 4 + 1][li];
        float4 p2 = redS[buf][quad * 4 + 2][li];
        float4 p3 = redS[buf][quad * 4 + 3][li];
        float N  = p0.x + p1.x + p2.x + p3.x;
        float S1 = p0.y + p1.y + p2.y + p3.y;
        float S2 = p0.z + p1.z + p2.z + p3.z;
        N  += __shfl_xor(N, 16, 64);  N  += __shfl_xor(N, 32, 64);
        S1 += __shfl_xor(S1, 16, 64); S1 += __shfl_xor(S1, 32, 64);
        S2 += __shfl_xor(S2, 16, 64); S2 += __shfl_xor(S2, 32, 64);

        const float disc = S1 * S1 - N * (S2 - 1.0f);
        float tn;
        if (disc >= 0.0f) {
            tn = (S1 - sqrtf(disc)) / N;
        } else {
            const float g = S1 - N * tau;
            const float f = S2 - tau * (2.0f * S1 - N * tau);
            tn = tau + (f - 1.0f) / (2.0f * g);
        }
        const bool cf = (tn == tau);
        tau = tn;
        buf ^= 1;
        if (__all(cf)) break;            // identical in every wave
    }

    // ---- emit p = clip(z - tau, 0)^2 (f32 math), float4v NT stores ----
    float* orow = out + (size_t)(r0 + li) * 8192 + c0;
#pragma unroll
    for (int tp = 0; tp < 32; tp += 2) {
        union { unsigned u; __half2 h2; } w0, w1, w2, w3;
        AREAD4(w0.u, w1.u, w2.u, w3.u,
               zh[tp * 2 + 0], zh[tp * 2 + 1], zh[tp * 2 + 2], zh[tp * 2 + 3]);
        float2 f0 = __half22float2(w0.h2);
        float2 f1 = __half22float2(w1.h2);
        float2 f2 = __half22float2(w2.h2);
        float2 f3 = __half22float2(w3.h2);
        float4v pv0, pv1;
        float d;
        d = fmaxf(f0.x - tau, 0.f); pv0.x = d * d;
        d = fmaxf(f0.y - tau, 0.f); pv0.y = d * d;
        d = fmaxf(f1.x - tau, 0.f); pv0.z = d * d;
        d = fmaxf(f1.y - tau, 0.f); pv0.w = d * d;
        d = fmaxf(f2.x - tau, 0.f); pv1.x = d * d;
        d = fmaxf(f2.y - tau, 0.f); pv1.y = d * d;
        d = fmaxf(f3.x - tau, 0.f); pv1.z = d * d;
        d = fmaxf(f3.y - tau, 0.f); pv1.w = d * d;
        __builtin_nontemporal_store(pv0, (float4v*)(orow + tp * 16 + quad * 4));
        __builtin_nontemporal_store(pv1, (float4v*)(orow + (tp + 1) * 16 + quad * 4));
    }
}

// ---------------------------------------------------------------------------
extern "C" void kernel_launch(void* const* d_in, const int* in_sizes, int n_in,
                              void* d_out, int out_size, void* d_ws, size_t ws_size,
                              hipStream_t stream)
{
    const float* edge_repr = (const float*)d_in[0];
    const float* sub_repr  = (const float*)d_in[1];
    const float* W_sub     = (const float*)d_in[2];
    const float* b_sub     = (const float*)d_in[3];
    const float* W_edge    = (const float*)d_in[4];
    const float* b_edge    = (const float*)d_in[5];
    const float* log_scale = (const float*)d_in[6];
    float* out = (float*)d_out;

    unsigned short* subE  = (unsigned short*)d_ws;                 // 3 MB
    unsigned short* edgeE = subE + (size_t)8192 * 192;             // 3 MB

    proj_norm_kernel<<<dim3(256, 2), 256, 0, stream>>>(
        sub_repr, edge_repr, W_sub, b_sub, W_edge, b_edge, subE, edgeE);

    fused_score_entmax_kernel<<<dim3(512), 1024, 0, stream>>>(
        subE, edgeE, log_scale, out);
}

// Round 8
// 422.166 us; speedup vs baseline: 1.4963x; 1.4633x over previous
//
#include <hip/hip_runtime.h>
#include <hip/hip_fp16.h>
#include <math.h>

#define ITERS 12

typedef __attribute__((ext_vector_type(8))) short short8;
typedef __attribute__((ext_vector_type(4))) float float4v;
typedef _Float16 __attribute__((ext_vector_type(2))) half2v;

static __device__ inline unsigned short f2bf(float f) {
    union { float f; unsigned int u; } c; c.f = f;
    unsigned int u = c.u;
    u += 0x7fffu + ((u >> 16) & 1u);          // round-to-nearest-even
    return (unsigned short)(u >> 16);
}
static __device__ inline float bf2f(unsigned short h) {
    union { float f; unsigned int u; } c; c.u = ((unsigned int)h) << 16;
    return c.f;
}

// ---------------------------------------------------------------------------
// Kernel A (r0 verbatim): P = l2_normalize(X @ W^T + b), emitted as
// split-bf16 rows of 192:
//   sub:  [hi(64) | lo(64) | hi(64)]
//   edge: [hi(64) | hi(64) | lo(64)]
// so that subE @ edgeE^T over K=192 = Ah*Bh + Al*Bh + Ah*Bl (lo*lo dropped).
// ---------------------------------------------------------------------------
__global__ __launch_bounds__(256) void proj_norm_kernel(
    const float* __restrict__ Xsub, const float* __restrict__ Xedge,
    const float* __restrict__ Wsub, const float* __restrict__ bsub,
    const float* __restrict__ Wedge, const float* __restrict__ bedge,
    unsigned short* __restrict__ subE, unsigned short* __restrict__ edgeE)
{
    const int mat = blockIdx.y;
    const float* X  = mat ? Xedge : Xsub;
    const float* W  = mat ? Wedge : Wsub;
    const float* Bv = mat ? bedge : bsub;
    unsigned short* OUT = mat ? edgeE : subE;

    const int r0 = blockIdx.x * 32;
    const int t  = threadIdx.x;
    const int tx = t & 15, ty = t >> 4;

    __shared__ float xs[64 * 34];   // [k][row(32)+pad]
    __shared__ float ws[64 * 68];   // [k][col(64)+pad]

    float acc[2][4] = {};

    for (int ch = 0; ch < 8; ++ch) {
        const int kb = ch * 64;
#pragma unroll
        for (int i = 0; i < 2; ++i) {
            int e = t + 256 * i;            // 512 float4 (32 rows x 16 kq)
            int row = e & 31, kq = e >> 5;
            float4 xv = *(const float4*)(X + (size_t)(r0 + row) * 512 + kb + kq * 4);
            xs[(kq * 4 + 0) * 34 + row] = xv.x;
            xs[(kq * 4 + 1) * 34 + row] = xv.y;
            xs[(kq * 4 + 2) * 34 + row] = xv.z;
            xs[(kq * 4 + 3) * 34 + row] = xv.w;
        }
#pragma unroll
        for (int i = 0; i < 4; ++i) {
            int e = t + 256 * i;            // 1024 float4 (64 cols x 16 kq)
            int col = e & 63, kq = e >> 6;
            float4 wv = *(const float4*)(W + (size_t)col * 512 + kb + kq * 4);
            ws[(kq * 4 + 0) * 68 + col] = wv.x;
            ws[(kq * 4 + 1) * 68 + col] = wv.y;
            ws[(kq * 4 + 2) * 68 + col] = wv.z;
            ws[(kq * 4 + 3) * 68 + col] = wv.w;
        }
        __syncthreads();
#pragma unroll 8
        for (int k = 0; k < 64; ++k) {
            const float2 a2 = *(const float2*)&xs[k * 34 + ty * 2];
            const float4 b4 = *(const float4*)&ws[k * 68 + tx * 4];
            acc[0][0] = fmaf(a2.x, b4.x, acc[0][0]);
            acc[0][1] = fmaf(a2.x, b4.y, acc[0][1]);
            acc[0][2] = fmaf(a2.x, b4.z, acc[0][2]);
            acc[0][3] = fmaf(a2.x, b4.w, acc[0][3]);
            acc[1][0] = fmaf(a2.y, b4.x, acc[1][0]);
            acc[1][1] = fmaf(a2.y, b4.y, acc[1][1]);
            acc[1][2] = fmaf(a2.y, b4.z, acc[1][2]);
            acc[1][3] = fmaf(a2.y, b4.w, acc[1][3]);
        }
        __syncthreads();
    }

    const float4 bb = *(const float4*)(Bv + tx * 4);
#pragma unroll
    for (int i = 0; i < 2; ++i) {
        acc[i][0] += bb.x; acc[i][1] += bb.y; acc[i][2] += bb.z; acc[i][3] += bb.w;
        float s = acc[i][0]*acc[i][0] + acc[i][1]*acc[i][1]
                + acc[i][2]*acc[i][2] + acc[i][3]*acc[i][3];
#pragma unroll
        for (int off = 1; off <= 8; off <<= 1)
            s += __shfl_xor(s, off, 64);
        const float inv = 1.0f / fmaxf(sqrtf(s), 1e-12f);

        unsigned short h[4], l[4];
#pragma unroll
        for (int j = 0; j < 4; ++j) {
            const float v = acc[i][j] * inv;
            h[j] = f2bf(v);
            l[j] = f2bf(v - bf2f(h[j]));
        }
        uint2 hp, lp;
        hp.x = (unsigned)h[0] | ((unsigned)h[1] << 16);
        hp.y = (unsigned)h[2] | ((unsigned)h[3] << 16);
        lp.x = (unsigned)l[0] | ((unsigned)l[1] << 16);
        lp.y = (unsigned)l[2] | ((unsigned)l[3] << 16);

        unsigned short* base = OUT + (size_t)(r0 + ty * 2 + i) * 192 + tx * 4;
        *(uint2*)(base)       = hp;
        *(uint2*)(base + 64)  = mat ? hp : lp;   // edge: hi ; sub: lo
        *(uint2*)(base + 128) = mat ? lp : hp;   // edge: lo ; sub: hi
    }
}

// ---------------------------------------------------------------------------
// Kernel B1 (r0 verbatim): z[s][e] = fp16( (subP[s].edgeP[e]) * scale / 2 )
// via bf16 GEMM over extended K=192.  Tile 128(s) x 64(e), grid (128, 64),
// 256 thr (4 waves).  K staged in 3 chunks of 64 (LDS stride 72, 27 KB).
// REVERT RATIONALE (r7): the fused design (r1-r7) never beat 371 us despite
// occupancy/asm/op-count fixes -- 1-block/CU phase serialization + 64-reg
// GEMM + volatile-AGPR scheduling poison.  The split B1+B2 pair measured
// ~210 us combined in r0; the 268 MB z round-trip it pays is cheaper than
// the fused kernel's structural overheads.
// ---------------------------------------------------------------------------
__global__ __launch_bounds__(256, 4) void score_mfma_kernel(
    const unsigned short* __restrict__ subE,
    const unsigned short* __restrict__ edgeE,
    const float* __restrict__ log_scale, __half* __restrict__ z)
{
    const int t    = threadIdx.x;
    const int lane = t & 63;
    const int wid  = t >> 6;
    const int li   = lane & 15;
    const int quad = lane >> 4;
    const int s0   = blockIdx.y * 128;
    const int e0   = blockIdx.x * 64;
    const int mrow0 = (wid & 1) * 64;
    const int ncol0 = (wid >> 1) * 32;

    __shared__ unsigned short aS[128 * 72];
    __shared__ unsigned short bS[64 * 72];

    float4v acc[4][2];
#pragma unroll
    for (int mi = 0; mi < 4; ++mi)
#pragma unroll
        for (int ni = 0; ni < 2; ++ni)
            acc[mi][ni] = (float4v){0.f, 0.f, 0.f, 0.f};

    for (int c = 0; c < 3; ++c) {
        if (c) __syncthreads();             // protect LDS reuse
#pragma unroll
        for (int i = 0; i < 4; ++i) {
            int e = t + 256 * i;            // 1024 f4 (128 rows x 8 offs)
            int row = e >> 3, off = e & 7;
            *(float4*)&aS[row * 72 + off * 8] =
                *(const float4*)(subE + (size_t)(s0 + row) * 192 + c * 64 + off * 8);
        }
#pragma unroll
        for (int i = 0; i < 2; ++i) {
            int e = t + 256 * i;            // 512 f4 (64 rows x 8 offs)
            int row = e >> 3, off = e & 7;
            *(float4*)&bS[row * 72 + off * 8] =
                *(const float4*)(edgeE + (size_t)(e0 + row) * 192 + c * 64 + off * 8);
        }
        __syncthreads();

#pragma unroll
        for (int ks = 0; ks < 2; ++ks) {
            short8 af[4], bfr[2];
#pragma unroll
            for (int mi = 0; mi < 4; ++mi)
                af[mi] = *(const short8*)&aS[(mrow0 + mi * 16 + li) * 72 + ks * 32 + quad * 8];
#pragma unroll
            for (int ni = 0; ni < 2; ++ni)
                bfr[ni] = *(const short8*)&bS[(ncol0 + ni * 16 + li) * 72 + ks * 32 + quad * 8];
#pragma unroll
            for (int mi = 0; mi < 4; ++mi)
#pragma unroll
                for (int ni = 0; ni < 2; ++ni)
                    acc[mi][ni] = __builtin_amdgcn_mfma_f32_16x16x32_bf16(
                        af[mi], bfr[ni], acc[mi][ni], 0, 0, 0);
        }
    }

    float sc = expf(log_scale[0]);
    sc = fminf(fmaxf(sc, 0.5f), 20.0f);
    const float zs = sc * 0.5f;             // z = scores/2

#pragma unroll
    for (int mi = 0; mi < 4; ++mi)
#pragma unroll
        for (int ni = 0; ni < 2; ++ni) {
            const int col = e0 + ncol0 + ni * 16 + li;
#pragma unroll
            for (int reg = 0; reg < 4; ++reg) {
                const int row = s0 + mrow0 + mi * 16 + quad * 4 + reg;
                z[(size_t)row * 8192 + col] = __float2half_rn(acc[mi][ni][reg] * zs);
            }
        }
}

// ---------------------------------------------------------------------------
// Kernel B2 (v2): rowwise exact 1.5-entmax on fp16 z.  One block per row,
// 256 threads, 32 halves/thread kept PACKED (16 uint words, half the regs
// of r0's f32 path).  Support scan in packed fp16 (validated r7, same
// absmax): __hgt2 mask + __hmul2 masked-z + __hadd2 packed count (exact,
// <=16/slot) + v_dot2_f32_f16 for s1/s2 (f32 accumulate; fp16*fp16 exact
// in f32).  ~85 VALU ops/thread/iter vs r0's ~192.  Same support-set
// iteration with exact quadratic solve + block-uniform early break.
// ---------------------------------------------------------------------------
__global__ __launch_bounds__(256) void entmax_fp16_kernel(
    const __half* __restrict__ z, float* __restrict__ out)
{
    const int row  = blockIdx.x;
    const int t    = threadIdx.x;
    const int lane = t & 63, wid = t >> 6;
    const __half* zr = z + (size_t)row * 8192;

    // 32 halves/thread as 16 packed words (4x 16B coalesced loads)
    unsigned zp[16];
#pragma unroll
    for (int c = 0; c < 4; ++c) {
        uint4 rd = *(const uint4*)(zr + c * 2048 + t * 8);
        zp[c * 4 + 0] = rd.x;
        zp[c * 4 + 1] = rd.y;
        zp[c * 4 + 2] = rd.z;
        zp[c * 4 + 3] = rd.w;
    }

    __shared__ float tblm[4];
    __shared__ float tbl[2][4][3];

    // ---- row max (f32 compare; cheap, once) ----
    float m = -1e30f;
#pragma unroll
    for (int j = 0; j < 16; ++j) {
        union { unsigned u; __half2 h2; } cv; cv.u = zp[j];
        float2 f = __half22float2(cv.h2);
        m = fmaxf(m, fmaxf(f.x, f.y));
    }
#pragma unroll
    for (int off = 32; off; off >>= 1) m = fmaxf(m, __shfl_xor(m, off, 64));
    if (lane == 0) tblm[wid] = m;
    __syncthreads();
    m = fmaxf(fmaxf(tblm[0], tblm[1]), fmaxf(tblm[2], tblm[3]));

    float tau = m - 1.0f;
    const half2v one2v = {(_Float16)1.0f, (_Float16)1.0f};

    for (int it = 0; it < ITERS; ++it) {
        float s1 = 0.f, s2 = 0.f;
        __half2 nh2 = __float2half2_rn(0.f);
        const __half2 tau2 = __float2half2_rn(tau);
#pragma unroll
        for (int j = 0; j < 16; ++j) {
            union U { unsigned u; __half2 h2; half2v v; };
            U a, mk, zm;
            a.u = zp[j];
            mk.h2 = __hgt2(a.h2, tau2);
            zm.h2 = __hmul2(mk.h2, a.h2);
            nh2 = __hadd2(nh2, mk.h2);
            s1 = __builtin_amdgcn_fdot2(zm.v, one2v, s1, false);
            s2 = __builtin_amdgcn_fdot2(zm.v, zm.v,  s2, false);
        }
        float2 nf = __half22float2(nh2);
        float n = nf.x + nf.y;
#pragma unroll
        for (int off = 32; off; off >>= 1) {
            n  += __shfl_xor(n,  off, 64);
            s1 += __shfl_xor(s1, off, 64);
            s2 += __shfl_xor(s2, off, 64);
        }
        if (lane == 0) {
            tbl[it & 1][wid][0] = n;
            tbl[it & 1][wid][1] = s1;
            tbl[it & 1][wid][2] = s2;
        }
        __syncthreads();
        float N = 0.f, S1 = 0.f, S2 = 0.f;
#pragma unroll
        for (int w = 0; w < 4; ++w) {
            N  += tbl[it & 1][w][0];
            S1 += tbl[it & 1][w][1];
            S2 += tbl[it & 1][w][2];
        }
        const float disc = S1 * S1 - N * (S2 - 1.0f);
        float tn;
        if (disc >= 0.0f) {
            tn = (S1 - sqrtf(disc)) / N;
        } else {
            const float g = S1 - N * tau;
            const float f = S2 - tau * (2.0f * S1 - N * tau);
            tn = tau + (f - 1.0f) / (2.0f * g);
        }
        if (tn == tau) break;
        tau = tn;
    }

    // ---- emit p = clip(z - tau, 0)^2 (f32 math), NT float4 stores ----
#pragma unroll
    for (int c = 0; c < 4; ++c) {
        float2 f0, f1, f2, f3;
        {
            union { unsigned u; __half2 h2; } cv;
            cv.u = zp[c * 4 + 0]; f0 = __half22float2(cv.h2);
            cv.u = zp[c * 4 + 1]; f1 = __half22float2(cv.h2);
            cv.u = zp[c * 4 + 2]; f2 = __half22float2(cv.h2);
            cv.u = zp[c * 4 + 3]; f3 = __half22float2(cv.h2);
        }
        float4v p0, p1; float d;
        d = fmaxf(f0.x - tau, 0.f); p0.x = d * d;
        d = fmaxf(f0.y - tau, 0.f); p0.y = d * d;
        d = fmaxf(f1.x - tau, 0.f); p0.z = d * d;
        d = fmaxf(f1.y - tau, 0.f); p0.w = d * d;
        d = fmaxf(f2.x - tau, 0.f); p1.x = d * d;
        d = fmaxf(f2.y - tau, 0.f); p1.y = d * d;
        d = fmaxf(f3.x - tau, 0.f); p1.z = d * d;
        d = fmaxf(f3.y - tau, 0.f); p1.w = d * d;
        float* op = out + (size_t)row * 8192 + c * 2048 + t * 8;
        __builtin_nontemporal_store(p0, (float4v*)op);
        __builtin_nontemporal_store(p1, (float4v*)(op + 4));
    }
}

// ---------------------------------------------------------------------------
extern "C" void kernel_launch(void* const* d_in, const int* in_sizes, int n_in,
                              void* d_out, int out_size, void* d_ws, size_t ws_size,
                              hipStream_t stream)
{
    const float* edge_repr = (const float*)d_in[0];
    const float* sub_repr  = (const float*)d_in[1];
    const float* W_sub     = (const float*)d_in[2];
    const float* b_sub     = (const float*)d_in[3];
    const float* W_edge    = (const float*)d_in[4];
    const float* b_edge    = (const float*)d_in[5];
    const float* log_scale = (const float*)d_in[6];
    float* out = (float*)d_out;

    unsigned short* subE  = (unsigned short*)d_ws;                 // 3 MB
    unsigned short* edgeE = subE + (size_t)8192 * 192;             // 3 MB
    __half*         zbuf  = (__half*)(edgeE + (size_t)8192 * 192); // 134 MB

    proj_norm_kernel<<<dim3(256, 2), 256, 0, stream>>>(
        sub_repr, edge_repr, W_sub, b_sub, W_edge, b_edge, subE, edgeE);

    score_mfma_kernel<<<dim3(128, 64), 256, 0, stream>>>(
        subE, edgeE, log_scale, zbuf);

    entmax_fp16_kernel<<<8192, 256, 0, stream>>>(zbuf, out);
}